// Round 6
// baseline (1750.138 us; speedup 1.0000x reference)
//
#include <hip/hip_runtime.h>
#include <hip/hip_bf16.h>
#include <math.h>

#define BQ 2
#define SEQL 4096
#define DM 512
#define DIN 1024
#define DSTATE 128
#define NH 16
#define HD 64
#define DCONV 4
#define CONVDIM 1280
#define DINPROJ 2320
#define CHUNKL 128
#define NCHUNK 32
#define ROWS (BQ*SEQL)   // 8192
#define NPAD 2432        // 19*128, padded in_proj N

typedef __attribute__((ext_vector_type(8))) short short8;
typedef __attribute__((ext_vector_type(4))) short short4v;
typedef __attribute__((ext_vector_type(4))) float f32x4;

__device__ __forceinline__ short bfs(float f) {
  __hip_bfloat16 h = __float2bfloat16(f);
  short s; __builtin_memcpy(&s, &h, 2); return s;
}

// ---------------- LayerNorm (+ optional bf16 copy of output) ----------------
__global__ __launch_bounds__(256) void ln_kernel(const float* __restrict__ in, const float* __restrict__ w,
                                                 const float* __restrict__ b, float* __restrict__ out,
                                                 __hip_bfloat16* __restrict__ outb) {
  int r = blockIdx.x;
  const float* x = in + (size_t)r * DM;
  float v[2];
  float s = 0.f, ss = 0.f;
  for (int i = 0; i < 2; i++) { v[i] = x[threadIdx.x + i*256]; s += v[i]; ss += v[i]*v[i]; }
  for (int o = 32; o > 0; o >>= 1) { s += __shfl_down(s, o); ss += __shfl_down(ss, o); }
  __shared__ float red[2][4];
  int lane = threadIdx.x & 63, wv = threadIdx.x >> 6;
  if (lane == 0) { red[0][wv] = s; red[1][wv] = ss; }
  __syncthreads();
  s  = red[0][0] + red[0][1] + red[0][2] + red[0][3];
  ss = red[1][0] + red[1][1] + red[1][2] + red[1][3];
  float mu = s * (1.f/DM);
  float var = ss * (1.f/DM) - mu*mu;
  float rstd = rsqrtf(var + 1e-5f);
  for (int i = 0; i < 2; i++) {
    int idx = threadIdx.x + i*256;
    float val = (v[i]-mu)*rstd*w[idx] + b[idx];
    out[(size_t)r*DM + idx] = val;
    if (outb) outb[(size_t)r*DM + idx] = __float2bfloat16(val);
  }
}

// ---------------- weight fp32 -> bf16 conversions (once per call) ----------------
__global__ __launch_bounds__(256) void cvt_wi(const float* __restrict__ Wi, __hip_bfloat16* __restrict__ out) {
  int idx = blockIdx.x*256 + threadIdx.x;   // 6*NPAD*512
  int l = idx / (NPAD*DM);
  int r = idx - l*(NPAD*DM);
  int n = r >> 9, k = r & 511;
  float v = (n < DINPROJ) ? Wi[(size_t)l*DINPROJ*DM + (size_t)n*DM + k] : 0.f;
  out[idx] = __float2bfloat16(v);
}
__global__ __launch_bounds__(256) void cvt_wo(const float* __restrict__ Wo, __hip_bfloat16* __restrict__ out) {
  size_t idx = (size_t)blockIdx.x*256 + threadIdx.x;  // 6*512*1024
  out[idx] = __float2bfloat16(Wo[idx]);
}

// ---------------- bf16 MFMA NT GEMM: C[M,N] = A[M,K] * B[N,K]^T (+C) ----------------
template<bool ADD>
__global__ __launch_bounds__(256) void gemm_bf16(const __hip_bfloat16* __restrict__ A,
                                                 const __hip_bfloat16* __restrict__ Bw,
                                                 float* __restrict__ C, int N, int K) {
  __shared__ __hip_bfloat16 sA[128*64];
  __shared__ __hip_bfloat16 sB[128*64];
  int tid = threadIdx.x;
  int w = tid >> 6, lane = tid & 63;
  int quad = lane >> 4, l16 = lane & 15;
  int row0 = blockIdx.y * 128, col0 = blockIdx.x * 128;
  int srow = lane >> 3;
  int schunk = lane & 7;
  f32x4 acc[4][4];
  #pragma unroll
  for (int i = 0; i < 4; i++)
    #pragma unroll
    for (int j = 0; j < 4; j++) acc[i][j] = (f32x4){0.f,0.f,0.f,0.f};
  int wrow = (w >> 1) * 64, wcol = (w & 1) * 64;
  for (int k0 = 0; k0 < K; k0 += 64) {
    #pragma unroll
    for (int j = 0; j < 4; j++) {
      int r = w*32 + j*8 + srow;
      int gc = (schunk ^ (r & 7)) * 8;
      const __hip_bfloat16* ga = A + (size_t)(row0 + r)*K + k0 + gc;
      __builtin_amdgcn_global_load_lds((const __attribute__((address_space(1))) void*)ga,
          (__attribute__((address_space(3))) void*)(sA + (w*32 + j*8)*64), 16, 0, 0);
      const __hip_bfloat16* gb = Bw + (size_t)(col0 + r)*K + k0 + gc;
      __builtin_amdgcn_global_load_lds((const __attribute__((address_space(1))) void*)gb,
          (__attribute__((address_space(3))) void*)(sB + (w*32 + j*8)*64), 16, 0, 0);
    }
    __syncthreads();
    #pragma unroll
    for (int ks = 0; ks < 64; ks += 32) {
      short8 af[4], bfv[4];
      #pragma unroll
      for (int mt = 0; mt < 4; mt++) {
        int r = wrow + mt*16 + l16;
        int cch = (ks/8 + quad) ^ (r & 7);
        af[mt] = *(const short8*)(sA + r*64 + cch*8);
      }
      #pragma unroll
      for (int nt = 0; nt < 4; nt++) {
        int r = wcol + nt*16 + l16;
        int cch = (ks/8 + quad) ^ (r & 7);
        bfv[nt] = *(const short8*)(sB + r*64 + cch*8);
      }
      #pragma unroll
      for (int mt = 0; mt < 4; mt++)
        #pragma unroll
        for (int nt = 0; nt < 4; nt++)
          acc[mt][nt] = __builtin_amdgcn_mfma_f32_16x16x32_bf16(af[mt], bfv[nt], acc[mt][nt], 0, 0, 0);
    }
    __syncthreads();
  }
  #pragma unroll
  for (int mt = 0; mt < 4; mt++) {
    int r = row0 + wrow + mt*16 + quad*4;
    #pragma unroll
    for (int nt = 0; nt < 4; nt++) {
      int cidx = col0 + wcol + nt*16 + l16;
      if (cidx < N) {
        float* cp = C + (size_t)r*N + cidx;
        #pragma unroll
        for (int rg = 0; rg < 4; rg++) {
          float v = acc[mt][nt][rg];
          size_t off = (size_t)rg*N;
          if (ADD) cp[off] += v; else cp[off] = v;
        }
      }
    }
  }
}

// ---------------- exact fp32 dt ----------------
__global__ __launch_bounds__(256) void dt_exact(const float* __restrict__ hn, const float* __restrict__ Wi,
                                                const float* __restrict__ dtb, float* __restrict__ dtout) {
  int r = blockIdx.x;
  __shared__ float sh[512];
  __shared__ float red[16][17];
  int t = threadIdx.x;
  sh[t] = hn[(size_t)r*DM + t];
  sh[t+256] = hn[(size_t)r*DM + t + 256];
  __syncthreads();
  int j = t >> 4, seg = t & 15;
  const float* wrow = Wi + (size_t)(2304 + j)*DM + seg*32;
  float p = 0.f;
  #pragma unroll
  for (int k = 0; k < 32; k++) p += sh[seg*32 + k] * wrow[k];
  red[j][seg] = p;
  __syncthreads();
  if (t < 16) {
    float v = 0.f;
    for (int s = 0; s < 16; s++) v += red[t][s];
    v += dtb[t];
    dtout[r*NH + t] = (v > 20.f) ? v : log1pf(__expf(v));
  }
}

// ---------------- depthwise causal conv, LDS-tiled: 32 l x 256 c per block ----------------
__global__ __launch_bounds__(256) void conv_tiled(const float* __restrict__ zx, const float* __restrict__ cw,
                                                  const float* __restrict__ cb, float* __restrict__ xBC) {
  __shared__ float tile[35][260];   // rows l0-3..l0+31, 260 stride: 16B-aligned f4 stores
  int c0 = blockIdx.x * 256;
  int r0 = blockIdx.y * 32;         // global row
  int b = r0 >> 12, l0 = r0 & 4095;
  int t = threadIdx.x;
  for (int i = t; i < 35*64; i += 256) {
    int lr = i >> 6, c4 = (i & 63) * 4;
    int l = l0 - 3 + lr;
    float4 v = make_float4(0.f, 0.f, 0.f, 0.f);
    if (l >= 0) v = *(const float4*)(zx + ((size_t)(b<<12) + l)*DINPROJ + 1024 + c0 + c4);
    *(float4*)&tile[lr][c4] = v;
  }
  __syncthreads();
  int c = c0 + t;
  float w0 = cw[c*4+0], w1 = cw[c*4+1], w2 = cw[c*4+2], w3 = cw[c*4+3];
  float bias = cb[c];
  float x0 = tile[0][t], x1 = tile[1][t], x2 = tile[2][t];
  for (int l = 0; l < 32; l++) {
    float x3 = tile[l+3][t];
    float acc = bias + w0*x0 + w1*x1 + w2*x2 + w3*x3;
    xBC[(size_t)(r0 + l)*CONVDIM + c] = acc / (1.f + __expf(-acc));
    x0 = x1; x1 = x2; x2 = x3;
  }
}

// ---------------- SSD intra-chunk, MFMA, 1024 threads / 16 waves ----------------
// 136-short row stride (272B, 16B-aligned): direct short8/b128 fragment reads
// (identical layout to the R3 run that passed). Transposed stagings write
// row-contiguous (wave = fixed row, 64 consecutive cols) -> conflict-free;
// transpose cost is scalar column-reads from L1/L2-hot global.
__global__ __launch_bounds__(1024) void ssd_intra_mfma(const float* __restrict__ xBC, const float* __restrict__ dt,
                                                       const float* __restrict__ Alog, float* __restrict__ Y,
                                                       float* __restrict__ states, float* __restrict__ acs_buf,
                                                       float* __restrict__ alast) {
  __shared__ short sC[128][136];    // C rows [q][n]; reused for M [q][s]
  __shared__ short sB[128][136];    // B rows [s][n]
  __shared__ short sBwt[128][136];  // (B*w)^T [n][q]
  __shared__ short sXt[64][136];    // X^T [p][q]  (X = xh*dt)
  __shared__ float sa[128], sdt_s[128], sw[128];
  int raw = blockIdx.x;
  int bc = (raw & 7) + ((raw >> 7) << 3);
  int h = (raw >> 3) & 15;
  int b = bc >> 5, c = bc & 31;
  int sblk = bc*16 + h;
  int t = threadIdx.x;
  int w = t >> 6, lane = t & 63, quad = lane >> 4, l16 = lane & 15;
  size_t row0 = (size_t)(b*SEQL + c*CHUNKL);
  float Ah = -__expf(Alog[h]);
  if (t < 128) sdt_s[t] = dt[(row0 + t)*NH + h];
  __syncthreads();
  if (t < 64) {
    float v0 = sdt_s[2*t] * Ah, v1 = sdt_s[2*t+1] * Ah;
    float s2 = v0 + v1;
    #pragma unroll
    for (int off = 1; off < 64; off <<= 1) {
      float tmp = __shfl_up(s2, off);
      if (t >= off) s2 += tmp;
    }
    float tot = __shfl(s2, 63);
    float pre = s2 - (v0 + v1);
    float a0 = pre + v0, a1 = pre + v0 + v1;
    sa[2*t] = a0; sa[2*t+1] = a1;
    sw[2*t] = __expf(tot - a0); sw[2*t+1] = __expf(tot - a1);
    acs_buf[(size_t)sblk*128 + 2*t]   = a0;
    acs_buf[(size_t)sblk*128 + 2*t+1] = a1;
    if (t == 63) alast[(b*NH + h)*NCHUNK + c] = tot;
  }
  __syncthreads();
  // B rows and C rows: float4 coalesced reads, row-contiguous LDS writes
  for (int i = t; i < 128*64; i += 1024) {
    int q = i >> 6, n4 = (i & 63) * 4;
    float4 v = *(const float4*)(xBC + (row0+q)*CONVDIM + DIN + n4);
    short4v pk = { bfs(v.x), bfs(v.y), bfs(v.z), bfs(v.w) };
    if (n4 < DSTATE) *(short4v*)&sB[q][n4] = pk;
    else             *(short4v*)&sC[q][n4 - DSTATE] = pk;
  }
  // X^T: wave = fixed p, 64 consecutive q -> contiguous LDS writes (no conflicts);
  // global reads are scalar column reads (L1/L2 hot: xBC rows just touched).
  for (int i = t; i < 64*128; i += 1024) {
    int p = i >> 7, q = i & 127;
    sXt[p][q] = bfs(xBC[(row0+q)*CONVDIM + h*HD + p] * sdt_s[q]);
  }
  // (B*w)^T: same pattern, wave = fixed n, consecutive q.
  for (int i = t; i < 128*128; i += 1024) {
    int n = i >> 7, q = i & 127;
    sBwt[n][q] = bfs(xBC[(row0+q)*CONVDIM + DIN + n] * sw[q]);
  }
  __syncthreads();
  // step1: G = C·B^T   (wave w: m-tile w>>1, n-tiles (w&1)*4..+3)
  int mt1 = w >> 1, nt1 = (w & 1) * 4;
  f32x4 g[4];
  #pragma unroll
  for (int j = 0; j < 4; j++) g[j] = (f32x4){0.f,0.f,0.f,0.f};
  #pragma unroll
  for (int ks = 0; ks < 128; ks += 32) {
    short8 af = *(const short8*)&sC[mt1*16 + l16][ks + quad*8];
    #pragma unroll
    for (int j = 0; j < 4; j++) {
      short8 bfv = *(const short8*)&sB[(nt1+j)*16 + l16][ks + quad*8];
      g[j] = __builtin_amdgcn_mfma_f32_16x16x32_bf16(af, bfv, g[j], 0, 0, 0);
    }
  }
  // step4: states = X^T·(Bw)  (wave w: p-tile w>>2, n-tiles (w&3)*2..+1)
  int pt4 = w >> 2, nt4 = (w & 3) * 2;
  f32x4 st[2];
  st[0] = (f32x4){0.f,0.f,0.f,0.f}; st[1] = (f32x4){0.f,0.f,0.f,0.f};
  #pragma unroll
  for (int ks = 0; ks < 128; ks += 32) {
    short8 af = *(const short8*)&sXt[pt4*16 + l16][ks + quad*8];
    #pragma unroll
    for (int j = 0; j < 2; j++) {
      short8 bfv = *(const short8*)&sBwt[(nt4+j)*16 + l16][ks + quad*8];
      st[j] = __builtin_amdgcn_mfma_f32_16x16x32_bf16(af, bfv, st[j], 0, 0, 0);
    }
  }
  __syncthreads();   // step1's sC reads done everywhere
  // write M = L ⊙ G into sC
  #pragma unroll
  for (int j = 0; j < 4; j++) {
    int s = (nt1+j)*16 + l16;
    #pragma unroll
    for (int rg = 0; rg < 4; rg++) {
      int q = mt1*16 + quad*4 + rg;
      float m = (s <= q) ? g[j][rg] * __expf(sa[q] - sa[s]) : 0.f;
      sC[q][s] = bfs(m);
    }
  }
  __syncthreads();
  // step3: Y_diag = M·X  (wave w: m-tile w>>1, p-tiles (w&1)*2..+1)
  int mt3 = w >> 1, pt3 = (w & 1) * 2;
  f32x4 y4[2];
  y4[0] = (f32x4){0.f,0.f,0.f,0.f}; y4[1] = (f32x4){0.f,0.f,0.f,0.f};
  #pragma unroll
  for (int ks = 0; ks < 128; ks += 32) {
    short8 af = *(const short8*)&sC[mt3*16 + l16][ks + quad*8];
    #pragma unroll
    for (int j = 0; j < 2; j++) {
      short8 bfv = *(const short8*)&sXt[(pt3+j)*16 + l16][ks + quad*8];
      y4[j] = __builtin_amdgcn_mfma_f32_16x16x32_bf16(af, bfv, y4[j], 0, 0, 0);
    }
  }
  #pragma unroll
  for (int j = 0; j < 2; j++) {
    int p = (pt3+j)*16 + l16;
    #pragma unroll
    for (int rg = 0; rg < 4; rg++) {
      int q = mt3*16 + quad*4 + rg;
      Y[(row0 + q)*DIN + h*HD + p] = y4[j][rg];
    }
  }
  float* sp = states + (size_t)sblk*(HD*DSTATE);
  #pragma unroll
  for (int j = 0; j < 2; j++) {
    int n = (nt4+j)*16 + l16;
    #pragma unroll
    for (int rg = 0; rg < 4; rg++) {
      int p = pt4*16 + quad*4 + rg;
      sp[(size_t)p*DSTATE + n] = st[j][rg];
    }
  }
}

// ---------------- inter-chunk scan ----------------
__global__ __launch_bounds__(256) void ssd_scan2(float* __restrict__ states, const float* __restrict__ alast) {
  int idx = blockIdx.x*256 + threadIdx.x;     // 2*16*8192
  int b = idx >> 17;
  int h = (idx >> 13) & 15;
  int pn = idx & 8191;
  const float* al = alast + (b*NH + h)*NCHUNK;
  float S = 0.f;
  for (int c = 0; c < NCHUNK; c++) {
    size_t base = ((size_t)((b*NCHUNK + c)*NH + h))*8192 + pn;
    float dec = __expf(al[c]);
    float tmp = states[base];
    states[base] = S;
    S = dec*S + tmp;
  }
}

// ---------------- SSD off-diagonal, MFMA, 512 threads / 8 waves ----------------
__global__ __launch_bounds__(512) void ssd_off_mfma(const float* __restrict__ xBC, const float* __restrict__ states,
                                                    const float* __restrict__ acs_buf, const float* __restrict__ Dvec,
                                                    float* __restrict__ Y) {
  __shared__ short sC[128][136];   // C rows [q][n]
  __shared__ short sS[64][136];    // S rows [p][n]
  __shared__ float sa[128];
  int raw = blockIdx.x;
  int bc = (raw & 7) + ((raw >> 7) << 3);
  int h = (raw >> 3) & 15;
  int b = bc >> 5, c = bc & 31;
  int sblk = bc*16 + h;
  int t = threadIdx.x;
  int w = t >> 6, lane = t & 63, quad = lane >> 4, l16 = lane & 15;
  size_t row0 = (size_t)(b*SEQL + c*CHUNKL);
  const float* sbase = states + (size_t)sblk*(HD*DSTATE);
  for (int i = t; i < 128*32; i += 512) {
    int q = i >> 5, n4 = (i & 31) * 4;
    float4 v = *(const float4*)(xBC + (row0+q)*CONVDIM + DIN + DSTATE + n4);
    short4v pk = { bfs(v.x), bfs(v.y), bfs(v.z), bfs(v.w) };
    *(short4v*)&sC[q][n4] = pk;
  }
  for (int i = t; i < 64*32; i += 512) {
    int p = i >> 5, n4 = (i & 31) * 4;
    float4 v = *(const float4*)(sbase + (size_t)p*DSTATE + n4);
    short4v pk = { bfs(v.x), bfs(v.y), bfs(v.z), bfs(v.w) };
    *(short4v*)&sS[p][n4] = pk;
  }
  if (t < 128) sa[t] = acs_buf[(size_t)sblk*128 + t];
  __syncthreads();
  // wave w: m-tile w (q-rows), 4 n-tiles (p)
  f32x4 acc[4];
  #pragma unroll
  for (int nt = 0; nt < 4; nt++) acc[nt] = (f32x4){0.f,0.f,0.f,0.f};
  #pragma unroll
  for (int ks = 0; ks < 128; ks += 32) {
    short8 af = *(const short8*)&sC[w*16 + l16][ks + quad*8];
    #pragma unroll
    for (int nt = 0; nt < 4; nt++) {
      short8 bfv = *(const short8*)&sS[nt*16 + l16][ks + quad*8];
      acc[nt] = __builtin_amdgcn_mfma_f32_16x16x32_bf16(af, bfv, acc[nt], 0, 0, 0);
    }
  }
  float Dh = Dvec[h];
  #pragma unroll
  for (int rg = 0; rg < 4; rg++) {
    int q = w*16 + quad*4 + rg;
    float ea = __expf(sa[q]);
    #pragma unroll
    for (int nt = 0; nt < 4; nt++) {
      int p = nt*16 + l16;
      size_t yi = (row0 + q)*DIN + h*HD + p;
      Y[yi] += ea*acc[nt][rg] + Dh*xBC[(row0+q)*CONVDIM + h*HD + p];
    }
  }
}

// ---------------- gate (silu(z)) + RMSNorm -> bf16 ----------------
__global__ __launch_bounds__(256) void gate_rms(const float* __restrict__ zx, const float* __restrict__ Y,
                                                const float* __restrict__ rw, __hip_bfloat16* __restrict__ out) {
  int r = blockIdx.x;
  int t = threadIdx.x;
  float yz[4];
  float ss = 0.f;
  for (int i = 0; i < 4; i++) {
    int idx = t + i*256;
    float z = zx[(size_t)r*DINPROJ + idx];
    float y = Y[(size_t)r*DIN + idx];
    float v = y * z / (1.f + __expf(-z));
    yz[i] = v; ss += v*v;
  }
  for (int o = 32; o > 0; o >>= 1) ss += __shfl_down(ss, o);
  __shared__ float red[4];
  int lane = t & 63, wv = t >> 6;
  if (lane == 0) red[wv] = ss;
  __syncthreads();
  ss = red[0]+red[1]+red[2]+red[3];
  float rs = rsqrtf(ss*(1.f/DIN) + 1e-5f);
  for (int i = 0; i < 4; i++) {
    int idx = t + i*256;
    out[(size_t)r*DIN + idx] = __float2bfloat16(yz[i]*rs*rw[idx]);
  }
}

extern "C" void kernel_launch(void* const* d_in, const int* in_sizes, int n_in,
                              void* d_out, int out_size, void* d_ws, size_t ws_size,
                              hipStream_t stream) {
  (void)in_sizes; (void)n_in; (void)out_size; (void)ws_size;
  const float* x    = (const float*)d_in[0];
  const float* Wi   = (const float*)d_in[1];
  const float* cw   = (const float*)d_in[2];
  const float* cb   = (const float*)d_in[3];
  const float* dtb  = (const float*)d_in[4];
  const float* Alog = (const float*)d_in[5];
  const float* Dv   = (const float*)d_in[6];
  const float* rw   = (const float*)d_in[7];
  const float* Wo   = (const float*)d_in[8];
  const float* lnw  = (const float*)d_in[9];
  const float* lnb  = (const float*)d_in[10];
  const float* flnw = (const float*)d_in[11];
  const float* flnb = (const float*)d_in[12];
  float* out = (float*)d_out;

  float* p = (float*)d_ws;
  float* buf_h   = p; p += (size_t)ROWS*DM;
  float* buf_hn  = p; p += (size_t)ROWS*DM;
  float* buf_zx  = p; p += (size_t)ROWS*DINPROJ;
  float* buf_xBC = p; p += (size_t)ROWS*CONVDIM;
  float* buf_dt  = p; p += (size_t)ROWS*NH;
  float* buf_Y   = p; p += (size_t)ROWS*DIN;
  float* buf_st  = p; p += (size_t)BQ*NCHUNK*NH*HD*DSTATE;
  float* buf_acs = p; p += (size_t)BQ*NCHUNK*NH*CHUNKL;
  float* buf_al  = p; p += (size_t)BQ*NH*NCHUNK;
  __hip_bfloat16* bp = (__hip_bfloat16*)p;
  __hip_bfloat16* wi_b = bp; bp += (size_t)6*NPAD*DM;
  __hip_bfloat16* wo_b = bp; bp += (size_t)6*DM*DIN;
  __hip_bfloat16* hn_b = bp; bp += (size_t)ROWS*DM;
  __hip_bfloat16* y_b  = bp; bp += (size_t)ROWS*DIN;

  hipMemcpyAsync(buf_h, x, (size_t)ROWS*DM*sizeof(float), hipMemcpyDeviceToDevice, stream);
  cvt_wi<<<6*NPAD*DM/256, 256, 0, stream>>>(Wi, wi_b);
  cvt_wo<<<6*DM*DIN/256, 256, 0, stream>>>(Wo, wo_b);

  for (int i = 0; i < 6; i++) {
    ln_kernel<<<ROWS, 256, 0, stream>>>(buf_h, lnw + i*DM, lnb + i*DM, buf_hn, hn_b);
    dt_exact<<<ROWS, 256, 0, stream>>>(buf_hn, Wi + (size_t)i*DINPROJ*DM, dtb + i*NH, buf_dt);
    gemm_bf16<false><<<dim3(NPAD/128, ROWS/128), 256, 0, stream>>>(
        hn_b, wi_b + (size_t)i*NPAD*DM, buf_zx, DINPROJ, DM);
    conv_tiled<<<dim3(CONVDIM/256, ROWS/32), 256, 0, stream>>>(
        buf_zx, cw + (size_t)i*CONVDIM*DCONV, cb + i*CONVDIM, buf_xBC);
    ssd_intra_mfma<<<BQ*NCHUNK*NH, 1024, 0, stream>>>(
        buf_xBC, buf_dt, Alog + i*NH, buf_Y, buf_st, buf_acs, buf_al);
    ssd_scan2<<<BQ*NH*HD*DSTATE/256, 256, 0, stream>>>(buf_st, buf_al);
    ssd_off_mfma<<<BQ*NCHUNK*NH, 512, 0, stream>>>(buf_xBC, buf_st, buf_acs, Dv + i*NH, buf_Y);
    gate_rms<<<ROWS, 256, 0, stream>>>(buf_zx, buf_Y, rw + i*DIN, y_b);
    gemm_bf16<true><<<dim3(DM/128, ROWS/128), 256, 0, stream>>>(
        y_b, wo_b + (size_t)i*DM*DIN, buf_h, DM, DIN);
  }
  ln_kernel<<<ROWS, 256, 0, stream>>>(buf_h, flnw, flnb, out, nullptr);
}

// Round 8
// 1507.693 us; speedup vs baseline: 1.1608x; 1.1608x over previous
//
#include <hip/hip_runtime.h>
#include <hip/hip_bf16.h>
#include <math.h>

#define BQ 2
#define SEQL 4096
#define DM 512
#define DIN 1024
#define DSTATE 128
#define NH 16
#define HD 64
#define DCONV 4
#define CONVDIM 1280
#define DINPROJ 2320
#define CHUNKL 128
#define NCHUNK 32
#define ROWS (BQ*SEQL)   // 8192
#define NPAD 2432        // 19*128, padded in_proj N

typedef __attribute__((ext_vector_type(8))) short short8;
typedef __attribute__((ext_vector_type(4))) short short4v;
typedef __attribute__((ext_vector_type(4))) float f32x4;

__device__ __forceinline__ short bfs(float f) {
  __hip_bfloat16 h = __float2bfloat16(f);
  short s; __builtin_memcpy(&s, &h, 2); return s;
}
__device__ __forceinline__ float sbf(short s) {
  __hip_bfloat16 h; __builtin_memcpy(&h, &s, 2); return __bfloat162float(h);
}

// ---------------- LayerNorm (+ optional bf16 copy of output) ----------------
__global__ __launch_bounds__(256) void ln_kernel(const float* __restrict__ in, const float* __restrict__ w,
                                                 const float* __restrict__ b, float* __restrict__ out,
                                                 __hip_bfloat16* __restrict__ outb) {
  int r = blockIdx.x;
  const float* x = in + (size_t)r * DM;
  float v[2];
  float s = 0.f, ss = 0.f;
  for (int i = 0; i < 2; i++) { v[i] = x[threadIdx.x + i*256]; s += v[i]; ss += v[i]*v[i]; }
  for (int o = 32; o > 0; o >>= 1) { s += __shfl_down(s, o); ss += __shfl_down(ss, o); }
  __shared__ float red[2][4];
  int lane = threadIdx.x & 63, wv = threadIdx.x >> 6;
  if (lane == 0) { red[0][wv] = s; red[1][wv] = ss; }
  __syncthreads();
  s  = red[0][0] + red[0][1] + red[0][2] + red[0][3];
  ss = red[1][0] + red[1][1] + red[1][2] + red[1][3];
  float mu = s * (1.f/DM);
  float var = ss * (1.f/DM) - mu*mu;
  float rstd = rsqrtf(var + 1e-5f);
  for (int i = 0; i < 2; i++) {
    int idx = threadIdx.x + i*256;
    float val = (v[i]-mu)*rstd*w[idx] + b[idx];
    out[(size_t)r*DM + idx] = val;
    if (outb) outb[(size_t)r*DM + idx] = __float2bfloat16(val);
  }
}

// ---------------- weight fp32 -> bf16 conversions (once per call) ----------------
__global__ __launch_bounds__(256) void cvt_wi(const float* __restrict__ Wi, __hip_bfloat16* __restrict__ out) {
  int idx = blockIdx.x*256 + threadIdx.x;   // 6*NPAD*512
  int l = idx / (NPAD*DM);
  int r = idx - l*(NPAD*DM);
  int n = r >> 9, k = r & 511;
  float v = (n < DINPROJ) ? Wi[(size_t)l*DINPROJ*DM + (size_t)n*DM + k] : 0.f;
  out[idx] = __float2bfloat16(v);
}
__global__ __launch_bounds__(256) void cvt_wo(const float* __restrict__ Wo, __hip_bfloat16* __restrict__ out) {
  size_t idx = (size_t)blockIdx.x*256 + threadIdx.x;  // 6*512*1024
  out[idx] = __float2bfloat16(Wo[idx]);
}

// ---------------- bf16 MFMA NT GEMM, bf16 output: C[M,N] = A[M,K] * B[N,K]^T ----------------
__global__ __launch_bounds__(256) void gemm_nt_obf16(const __hip_bfloat16* __restrict__ A,
                                                     const __hip_bfloat16* __restrict__ Bw,
                                                     __hip_bfloat16* __restrict__ C, int N, int K) {
  __shared__ __hip_bfloat16 sA[128*64];
  __shared__ __hip_bfloat16 sB[128*64];
  int tid = threadIdx.x;
  int w = tid >> 6, lane = tid & 63;
  int quad = lane >> 4, l16 = lane & 15;
  int row0 = blockIdx.y * 128, col0 = blockIdx.x * 128;
  int srow = lane >> 3;
  int schunk = lane & 7;
  f32x4 acc[4][4];
  #pragma unroll
  for (int i = 0; i < 4; i++)
    #pragma unroll
    for (int j = 0; j < 4; j++) acc[i][j] = (f32x4){0.f,0.f,0.f,0.f};
  int wrow = (w >> 1) * 64, wcol = (w & 1) * 64;
  for (int k0 = 0; k0 < K; k0 += 64) {
    #pragma unroll
    for (int j = 0; j < 4; j++) {
      int r = w*32 + j*8 + srow;
      int gc = (schunk ^ (r & 7)) * 8;
      const __hip_bfloat16* ga = A + (size_t)(row0 + r)*K + k0 + gc;
      __builtin_amdgcn_global_load_lds((const __attribute__((address_space(1))) void*)ga,
          (__attribute__((address_space(3))) void*)(sA + (w*32 + j*8)*64), 16, 0, 0);
      const __hip_bfloat16* gb = Bw + (size_t)(col0 + r)*K + k0 + gc;
      __builtin_amdgcn_global_load_lds((const __attribute__((address_space(1))) void*)gb,
          (__attribute__((address_space(3))) void*)(sB + (w*32 + j*8)*64), 16, 0, 0);
    }
    __syncthreads();
    #pragma unroll
    for (int ks = 0; ks < 64; ks += 32) {
      short8 af[4], bfv[4];
      #pragma unroll
      for (int mt = 0; mt < 4; mt++) {
        int r = wrow + mt*16 + l16;
        int cch = (ks/8 + quad) ^ (r & 7);
        af[mt] = *(const short8*)(sA + r*64 + cch*8);
      }
      #pragma unroll
      for (int nt = 0; nt < 4; nt++) {
        int r = wcol + nt*16 + l16;
        int cch = (ks/8 + quad) ^ (r & 7);
        bfv[nt] = *(const short8*)(sB + r*64 + cch*8);
      }
      #pragma unroll
      for (int mt = 0; mt < 4; mt++)
        #pragma unroll
        for (int nt = 0; nt < 4; nt++)
          acc[mt][nt] = __builtin_amdgcn_mfma_f32_16x16x32_bf16(af[mt], bfv[nt], acc[mt][nt], 0, 0, 0);
    }
    __syncthreads();
  }
  #pragma unroll
  for (int mt = 0; mt < 4; mt++) {
    int r = row0 + wrow + mt*16 + quad*4;
    #pragma unroll
    for (int nt = 0; nt < 4; nt++) {
      int cidx = col0 + wcol + nt*16 + l16;
      if (cidx < N) {
        __hip_bfloat16* cp = C + (size_t)r*N + cidx;
        #pragma unroll
        for (int rg = 0; rg < 4; rg++)
          cp[(size_t)rg*N] = __float2bfloat16(acc[mt][nt][rg]);
      }
    }
  }
}

// ---------------- bf16 MFMA NT GEMM, fp32 accumulate-add output ----------------
__global__ __launch_bounds__(256) void gemm_nt_addf32(const __hip_bfloat16* __restrict__ A,
                                                      const __hip_bfloat16* __restrict__ Bw,
                                                      float* __restrict__ C, int N, int K) {
  __shared__ __hip_bfloat16 sA[128*64];
  __shared__ __hip_bfloat16 sB[128*64];
  int tid = threadIdx.x;
  int w = tid >> 6, lane = tid & 63;
  int quad = lane >> 4, l16 = lane & 15;
  int row0 = blockIdx.y * 128, col0 = blockIdx.x * 128;
  int srow = lane >> 3;
  int schunk = lane & 7;
  f32x4 acc[4][4];
  #pragma unroll
  for (int i = 0; i < 4; i++)
    #pragma unroll
    for (int j = 0; j < 4; j++) acc[i][j] = (f32x4){0.f,0.f,0.f,0.f};
  int wrow = (w >> 1) * 64, wcol = (w & 1) * 64;
  for (int k0 = 0; k0 < K; k0 += 64) {
    #pragma unroll
    for (int j = 0; j < 4; j++) {
      int r = w*32 + j*8 + srow;
      int gc = (schunk ^ (r & 7)) * 8;
      const __hip_bfloat16* ga = A + (size_t)(row0 + r)*K + k0 + gc;
      __builtin_amdgcn_global_load_lds((const __attribute__((address_space(1))) void*)ga,
          (__attribute__((address_space(3))) void*)(sA + (w*32 + j*8)*64), 16, 0, 0);
      const __hip_bfloat16* gb = Bw + (size_t)(col0 + r)*K + k0 + gc;
      __builtin_amdgcn_global_load_lds((const __attribute__((address_space(1))) void*)gb,
          (__attribute__((address_space(3))) void*)(sB + (w*32 + j*8)*64), 16, 0, 0);
    }
    __syncthreads();
    #pragma unroll
    for (int ks = 0; ks < 64; ks += 32) {
      short8 af[4], bfv[4];
      #pragma unroll
      for (int mt = 0; mt < 4; mt++) {
        int r = wrow + mt*16 + l16;
        int cch = (ks/8 + quad) ^ (r & 7);
        af[mt] = *(const short8*)(sA + r*64 + cch*8);
      }
      #pragma unroll
      for (int nt = 0; nt < 4; nt++) {
        int r = wcol + nt*16 + l16;
        int cch = (ks/8 + quad) ^ (r & 7);
        bfv[nt] = *(const short8*)(sB + r*64 + cch*8);
      }
      #pragma unroll
      for (int mt = 0; mt < 4; mt++)
        #pragma unroll
        for (int nt = 0; nt < 4; nt++)
          acc[mt][nt] = __builtin_amdgcn_mfma_f32_16x16x32_bf16(af[mt], bfv[nt], acc[mt][nt], 0, 0, 0);
    }
    __syncthreads();
  }
  #pragma unroll
  for (int mt = 0; mt < 4; mt++) {
    int r = row0 + wrow + mt*16 + quad*4;
    #pragma unroll
    for (int nt = 0; nt < 4; nt++) {
      int cidx = col0 + wcol + nt*16 + l16;
      if (cidx < N) {
        float* cp = C + (size_t)r*N + cidx;
        #pragma unroll
        for (int rg = 0; rg < 4; rg++)
          cp[(size_t)rg*N] += acc[mt][nt][rg];
      }
    }
  }
}

// ---------------- exact fp32 dt (from fp32 hn + fp32 Wi rows) ----------------
__global__ __launch_bounds__(256) void dt_exact(const float* __restrict__ hn, const float* __restrict__ Wi,
                                                const float* __restrict__ dtb, float* __restrict__ dtout) {
  int r = blockIdx.x;
  __shared__ float sh[512];
  __shared__ float red[16][17];
  int t = threadIdx.x;
  sh[t] = hn[(size_t)r*DM + t];
  sh[t+256] = hn[(size_t)r*DM + t + 256];
  __syncthreads();
  int j = t >> 4, seg = t & 15;
  const float* wrow = Wi + (size_t)(2304 + j)*DM + seg*32;
  float p = 0.f;
  #pragma unroll
  for (int k = 0; k < 32; k++) p += sh[seg*32 + k] * wrow[k];
  red[j][seg] = p;
  __syncthreads();
  if (t < 16) {
    float v = 0.f;
    for (int s = 0; s < 16; s++) v += red[t][s];
    v += dtb[t];
    dtout[r*NH + t] = (v > 20.f) ? v : log1pf(__expf(v));
  }
}

// ---------------- depthwise causal conv, LDS-tiled, bf16 input ----------------
__global__ __launch_bounds__(256) void conv_tiled(const __hip_bfloat16* __restrict__ zx, const float* __restrict__ cw,
                                                  const float* __restrict__ cb, float* __restrict__ xBC) {
  __shared__ float tile[35][260];
  int c0 = blockIdx.x * 256;
  int r0 = blockIdx.y * 32;
  int b = r0 >> 12, l0 = r0 & 4095;
  int t = threadIdx.x;
  for (int i = t; i < 35*64; i += 256) {
    int lr = i >> 6, c4 = (i & 63) * 4;
    int l = l0 - 3 + lr;
    float4 v = make_float4(0.f, 0.f, 0.f, 0.f);
    if (l >= 0) {
      short4v s = *(const short4v*)((const short*)zx + ((size_t)(b<<12) + l)*DINPROJ + 1024 + c0 + c4);
      v = make_float4(sbf(s[0]), sbf(s[1]), sbf(s[2]), sbf(s[3]));
    }
    *(float4*)&tile[lr][c4] = v;
  }
  __syncthreads();
  int c = c0 + t;
  float w0 = cw[c*4+0], w1 = cw[c*4+1], w2 = cw[c*4+2], w3 = cw[c*4+3];
  float bias = cb[c];
  float x0 = tile[0][t], x1 = tile[1][t], x2 = tile[2][t];
  for (int l = 0; l < 32; l++) {
    float x3 = tile[l+3][t];
    float acc = bias + w0*x0 + w1*x1 + w2*x2 + w3*x3;
    xBC[(size_t)(r0 + l)*CONVDIM + c] = acc / (1.f + __expf(-acc));
    x0 = x1; x1 = x2; x2 = x3;
  }
}

// ---------------- SSD intra-chunk, MFMA, 1024 threads / 16 waves (R3 layout) ----------------
__global__ __launch_bounds__(1024) void ssd_intra_mfma(const float* __restrict__ xBC, const float* __restrict__ dt,
                                                       const float* __restrict__ Alog, float* __restrict__ Y,
                                                       float* __restrict__ states, float* __restrict__ acs_buf,
                                                       float* __restrict__ alast) {
  __shared__ short sC[128][136];    // C rows [q][n]; reused for M [q][s]
  __shared__ short sB[128][136];    // B rows [s][n]
  __shared__ short sBwt[128][136];  // (B*w)^T [n][q]
  __shared__ short sXt[64][136];    // X^T [p][q]  (X = xh*dt)
  __shared__ float sa[128], sdt_s[128], sw[128];
  int raw = blockIdx.x;
  int bc = (raw & 7) + ((raw >> 7) << 3);
  int h = (raw >> 3) & 15;
  int b = bc >> 5, c = bc & 31;
  int sblk = bc*16 + h;
  int t = threadIdx.x;
  int w = t >> 6, lane = t & 63, quad = lane >> 4, l16 = lane & 15;
  size_t row0 = (size_t)(b*SEQL + c*CHUNKL);
  float Ah = -__expf(Alog[h]);
  if (t < 128) sdt_s[t] = dt[(row0 + t)*NH + h];
  __syncthreads();
  if (t < 64) {
    float v0 = sdt_s[2*t] * Ah, v1 = sdt_s[2*t+1] * Ah;
    float s2 = v0 + v1;
    #pragma unroll
    for (int off = 1; off < 64; off <<= 1) {
      float tmp = __shfl_up(s2, off);
      if (t >= off) s2 += tmp;
    }
    float tot = __shfl(s2, 63);
    float pre = s2 - (v0 + v1);
    float a0 = pre + v0, a1 = pre + v0 + v1;
    sa[2*t] = a0; sa[2*t+1] = a1;
    sw[2*t] = __expf(tot - a0); sw[2*t+1] = __expf(tot - a1);
    acs_buf[(size_t)sblk*128 + 2*t]   = a0;
    acs_buf[(size_t)sblk*128 + 2*t+1] = a1;
    if (t == 63) alast[(b*NH + h)*NCHUNK + c] = tot;
  }
  __syncthreads();
  // stage X^T (scaled by dt): float4 row reads, transposed scalar LDS writes
  for (int i = t; i < 128*16; i += 1024) {
    int q = i >> 4, p4 = (i & 15) * 4;
    float4 v = *(const float4*)(xBC + (row0+q)*CONVDIM + h*HD + p4);
    float d = sdt_s[q];
    sXt[p4+0][q] = bfs(v.x*d); sXt[p4+1][q] = bfs(v.y*d);
    sXt[p4+2][q] = bfs(v.z*d); sXt[p4+3][q] = bfs(v.w*d);
  }
  // stage B (rows + weighted transpose) and C (rows)
  for (int i = t; i < 128*64; i += 1024) {
    int q = i >> 6, n4 = (i & 63) * 4;
    float4 v = *(const float4*)(xBC + (row0+q)*CONVDIM + DIN + n4);
    if (n4 < DSTATE) {
      short4v pk = { bfs(v.x), bfs(v.y), bfs(v.z), bfs(v.w) };
      *(short4v*)&sB[q][n4] = pk;
      float wq = sw[q];
      sBwt[n4+0][q] = bfs(v.x*wq); sBwt[n4+1][q] = bfs(v.y*wq);
      sBwt[n4+2][q] = bfs(v.z*wq); sBwt[n4+3][q] = bfs(v.w*wq);
    } else {
      int n = n4 - DSTATE;
      short4v pk = { bfs(v.x), bfs(v.y), bfs(v.z), bfs(v.w) };
      *(short4v*)&sC[q][n] = pk;
    }
  }
  __syncthreads();
  // step1: G = C·B^T   (wave w: m-tile w>>1, n-tiles (w&1)*4..+3)
  int mt1 = w >> 1, nt1 = (w & 1) * 4;
  f32x4 g[4];
  #pragma unroll
  for (int j = 0; j < 4; j++) g[j] = (f32x4){0.f,0.f,0.f,0.f};
  #pragma unroll
  for (int ks = 0; ks < 128; ks += 32) {
    short8 af = *(const short8*)&sC[mt1*16 + l16][ks + quad*8];
    #pragma unroll
    for (int j = 0; j < 4; j++) {
      short8 bfv = *(const short8*)&sB[(nt1+j)*16 + l16][ks + quad*8];
      g[j] = __builtin_amdgcn_mfma_f32_16x16x32_bf16(af, bfv, g[j], 0, 0, 0);
    }
  }
  // step4: states = X^T·(Bw)  (wave w: p-tile w>>2, n-tiles (w&3)*2..+1)
  int pt4 = w >> 2, nt4 = (w & 3) * 2;
  f32x4 st[2];
  st[0] = (f32x4){0.f,0.f,0.f,0.f}; st[1] = (f32x4){0.f,0.f,0.f,0.f};
  #pragma unroll
  for (int ks = 0; ks < 128; ks += 32) {
    short8 af = *(const short8*)&sXt[pt4*16 + l16][ks + quad*8];
    #pragma unroll
    for (int j = 0; j < 2; j++) {
      short8 bfv = *(const short8*)&sBwt[(nt4+j)*16 + l16][ks + quad*8];
      st[j] = __builtin_amdgcn_mfma_f32_16x16x32_bf16(af, bfv, st[j], 0, 0, 0);
    }
  }
  __syncthreads();   // step1's sC reads done everywhere
  // write M = L ⊙ G into sC
  #pragma unroll
  for (int j = 0; j < 4; j++) {
    int s = (nt1+j)*16 + l16;
    #pragma unroll
    for (int rg = 0; rg < 4; rg++) {
      int q = mt1*16 + quad*4 + rg;
      float m = (s <= q) ? g[j][rg] * __expf(sa[q] - sa[s]) : 0.f;
      sC[q][s] = bfs(m);
    }
  }
  __syncthreads();
  // step3: Y_diag = M·X  (wave w: m-tile w>>1, p-tiles (w&1)*2..+1)
  int mt3 = w >> 1, pt3 = (w & 1) * 2;
  f32x4 y4[2];
  y4[0] = (f32x4){0.f,0.f,0.f,0.f}; y4[1] = (f32x4){0.f,0.f,0.f,0.f};
  #pragma unroll
  for (int ks = 0; ks < 128; ks += 32) {
    short8 af = *(const short8*)&sC[mt3*16 + l16][ks + quad*8];
    #pragma unroll
    for (int j = 0; j < 2; j++) {
      short8 bfv = *(const short8*)&sXt[(pt3+j)*16 + l16][ks + quad*8];
      y4[j] = __builtin_amdgcn_mfma_f32_16x16x32_bf16(af, bfv, y4[j], 0, 0, 0);
    }
  }
  #pragma unroll
  for (int j = 0; j < 2; j++) {
    int p = (pt3+j)*16 + l16;
    #pragma unroll
    for (int rg = 0; rg < 4; rg++) {
      int q = mt3*16 + quad*4 + rg;
      Y[(row0 + q)*DIN + h*HD + p] = y4[j][rg];
    }
  }
  float* sp = states + (size_t)sblk*(HD*DSTATE);
  #pragma unroll
  for (int j = 0; j < 2; j++) {
    int n = (nt4+j)*16 + l16;
    #pragma unroll
    for (int rg = 0; rg < 4; rg++) {
      int p = pt4*16 + quad*4 + rg;
      sp[(size_t)p*DSTATE + n] = st[j][rg];
    }
  }
}

// ---------------- inter-chunk scan ----------------
__global__ __launch_bounds__(256) void ssd_scan2(float* __restrict__ states, const float* __restrict__ alast) {
  int idx = blockIdx.x*256 + threadIdx.x;     // 2*16*8192
  int b = idx >> 17;
  int h = (idx >> 13) & 15;
  int pn = idx & 8191;
  const float* al = alast + (b*NH + h)*NCHUNK;
  float S = 0.f;
  for (int c = 0; c < NCHUNK; c++) {
    size_t base = ((size_t)((b*NCHUNK + c)*NH + h))*8192 + pn;
    float dec = __expf(al[c]);
    float tmp = states[base];
    states[base] = S;
    S = dec*S + tmp;
  }
}

// ---------------- SSD off-diagonal, MFMA, 512 threads / 8 waves ----------------
__global__ __launch_bounds__(512) void ssd_off_mfma(const float* __restrict__ xBC, const float* __restrict__ states,
                                                    const float* __restrict__ acs_buf, const float* __restrict__ Dvec,
                                                    float* __restrict__ Y) {
  __shared__ short sC[128][136];   // C rows [q][n]
  __shared__ short sS[64][136];    // S rows [p][n]
  __shared__ float sa[128];
  int raw = blockIdx.x;
  int bc = (raw & 7) + ((raw >> 7) << 3);
  int h = (raw >> 3) & 15;
  int b = bc >> 5, c = bc & 31;
  int sblk = bc*16 + h;
  int t = threadIdx.x;
  int w = t >> 6, lane = t & 63, quad = lane >> 4, l16 = lane & 15;
  size_t row0 = (size_t)(b*SEQL + c*CHUNKL);
  const float* sbase = states + (size_t)sblk*(HD*DSTATE);
  for (int i = t; i < 128*32; i += 512) {
    int q = i >> 5, n4 = (i & 31) * 4;
    float4 v = *(const float4*)(xBC + (row0+q)*CONVDIM + DIN + DSTATE + n4);
    short4v pk = { bfs(v.x), bfs(v.y), bfs(v.z), bfs(v.w) };
    *(short4v*)&sC[q][n4] = pk;
  }
  for (int i = t; i < 64*32; i += 512) {
    int p = i >> 5, n4 = (i & 31) * 4;
    float4 v = *(const float4*)(sbase + (size_t)p*DSTATE + n4);
    short4v pk = { bfs(v.x), bfs(v.y), bfs(v.z), bfs(v.w) };
    *(short4v*)&sS[p][n4] = pk;
  }
  if (t < 128) sa[t] = acs_buf[(size_t)sblk*128 + t];
  __syncthreads();
  f32x4 acc[4];
  #pragma unroll
  for (int nt = 0; nt < 4; nt++) acc[nt] = (f32x4){0.f,0.f,0.f,0.f};
  #pragma unroll
  for (int ks = 0; ks < 128; ks += 32) {
    short8 af = *(const short8*)&sC[w*16 + l16][ks + quad*8];
    #pragma unroll
    for (int nt = 0; nt < 4; nt++) {
      short8 bfv = *(const short8*)&sS[nt*16 + l16][ks + quad*8];
      acc[nt] = __builtin_amdgcn_mfma_f32_16x16x32_bf16(af, bfv, acc[nt], 0, 0, 0);
    }
  }
  float Dh = Dvec[h];
  #pragma unroll
  for (int rg = 0; rg < 4; rg++) {
    int q = w*16 + quad*4 + rg;
    float ea = __expf(sa[q]);
    #pragma unroll
    for (int nt = 0; nt < 4; nt++) {
      int p = nt*16 + l16;
      size_t yi = (row0 + q)*DIN + h*HD + p;
      Y[yi] += ea*acc[nt][rg] + Dh*xBC[(row0+q)*CONVDIM + h*HD + p];
    }
  }
}

// ---------------- gate (silu(z), z from bf16 zx) + RMSNorm -> bf16 ----------------
__global__ __launch_bounds__(256) void gate_rms(const __hip_bfloat16* __restrict__ zx, const float* __restrict__ Y,
                                                const float* __restrict__ rw, __hip_bfloat16* __restrict__ out) {
  int r = blockIdx.x;
  int t = threadIdx.x;
  float yz[4];
  float ss = 0.f;
  for (int i = 0; i < 4; i++) {
    int idx = t + i*256;
    float z = __bfloat162float(zx[(size_t)r*DINPROJ + idx]);
    float y = Y[(size_t)r*DIN + idx];
    float v = y * z / (1.f + __expf(-z));
    yz[i] = v; ss += v*v;
  }
  for (int o = 32; o > 0; o >>= 1) ss += __shfl_down(ss, o);
  __shared__ float red[4];
  int lane = t & 63, wv = t >> 6;
  if (lane == 0) red[wv] = ss;
  __syncthreads();
  ss = red[0]+red[1]+red[2]+red[3];
  float rs = rsqrtf(ss*(1.f/DIN) + 1e-5f);
  for (int i = 0; i < 4; i++) {
    int idx = t + i*256;
    out[(size_t)r*DIN + idx] = __float2bfloat16(yz[i]*rs*rw[idx]);
  }
}

extern "C" void kernel_launch(void* const* d_in, const int* in_sizes, int n_in,
                              void* d_out, int out_size, void* d_ws, size_t ws_size,
                              hipStream_t stream) {
  (void)in_sizes; (void)n_in; (void)out_size; (void)ws_size;
  const float* x    = (const float*)d_in[0];
  const float* Wi   = (const float*)d_in[1];
  const float* cw   = (const float*)d_in[2];
  const float* cb   = (const float*)d_in[3];
  const float* dtb  = (const float*)d_in[4];
  const float* Alog = (const float*)d_in[5];
  const float* Dv   = (const float*)d_in[6];
  const float* rw   = (const float*)d_in[7];
  const float* Wo   = (const float*)d_in[8];
  const float* lnw  = (const float*)d_in[9];
  const float* lnb  = (const float*)d_in[10];
  const float* flnw = (const float*)d_in[11];
  const float* flnb = (const float*)d_in[12];
  float* out = (float*)d_out;

  float* p = (float*)d_ws;
  float* buf_h   = p; p += (size_t)ROWS*DM;
  float* buf_hn  = p; p += (size_t)ROWS*DM;
  float* buf_xBC = p; p += (size_t)ROWS*CONVDIM;
  float* buf_dt  = p; p += (size_t)ROWS*NH;
  float* buf_Y   = p; p += (size_t)ROWS*DIN;
  float* buf_st  = p; p += (size_t)BQ*NCHUNK*NH*HD*DSTATE;
  float* buf_acs = p; p += (size_t)BQ*NCHUNK*NH*CHUNKL;
  float* buf_al  = p; p += (size_t)BQ*NH*NCHUNK;
  __hip_bfloat16* bp = (__hip_bfloat16*)p;
  __hip_bfloat16* buf_zx = bp; bp += (size_t)ROWS*DINPROJ;   // bf16 zx
  __hip_bfloat16* wi_b = bp; bp += (size_t)6*NPAD*DM;
  __hip_bfloat16* wo_b = bp; bp += (size_t)6*DM*DIN;
  __hip_bfloat16* hn_b = bp; bp += (size_t)ROWS*DM;
  __hip_bfloat16* y_b  = bp; bp += (size_t)ROWS*DIN;

  hipMemcpyAsync(buf_h, x, (size_t)ROWS*DM*sizeof(float), hipMemcpyDeviceToDevice, stream);
  cvt_wi<<<6*NPAD*DM/256, 256, 0, stream>>>(Wi, wi_b);
  cvt_wo<<<6*DM*DIN/256, 256, 0, stream>>>(Wo, wo_b);

  for (int i = 0; i < 6; i++) {
    ln_kernel<<<ROWS, 256, 0, stream>>>(buf_h, lnw + i*DM, lnb + i*DM, buf_hn, hn_b);
    dt_exact<<<ROWS, 256, 0, stream>>>(buf_hn, Wi + (size_t)i*DINPROJ*DM, dtb + i*NH, buf_dt);
    gemm_nt_obf16<<<dim3(NPAD/128, ROWS/128), 256, 0, stream>>>(
        hn_b, wi_b + (size_t)i*NPAD*DM, buf_zx, DINPROJ, DM);
    conv_tiled<<<dim3(CONVDIM/256, ROWS/32), 256, 0, stream>>>(
        buf_zx, cw + (size_t)i*CONVDIM*DCONV, cb + i*CONVDIM, buf_xBC);
    ssd_intra_mfma<<<BQ*NCHUNK*NH, 1024, 0, stream>>>(
        buf_xBC, buf_dt, Alog + i*NH, buf_Y, buf_st, buf_acs, buf_al);
    ssd_scan2<<<BQ*NH*HD*DSTATE/256, 256, 0, stream>>>(buf_st, buf_al);
    ssd_off_mfma<<<BQ*NCHUNK*NH, 512, 0, stream>>>(buf_xBC, buf_st, buf_acs, Dv + i*NH, buf_Y);
    gate_rms<<<ROWS, 256, 0, stream>>>(buf_zx, buf_Y, rw + i*DIN, y_b);
    gemm_nt_addf32<<<dim3(DM/128, ROWS/128), 256, 0, stream>>>(
        y_b, wo_b + (size_t)i*DM*DIN, buf_h, DM, DIN);
  }
  ln_kernel<<<ROWS, 256, 0, stream>>>(buf_h, flnw, flnb, out, nullptr);
}